// Round 14
// baseline (1003.013 us; speedup 1.0000x reference)
//
#include <hip/hip_runtime.h>
#include <hip/hip_bf16.h>

#define E_ 8
#define H_ 2048
#define D_ 4096
#define R_ 8
#define T_ 2048
#define TWO_D_ 8192
#define SCALE_ 2.0f

typedef __attribute__((ext_vector_type(8))) short short8;
typedef __attribute__((ext_vector_type(4))) float f32x4;

__device__ __forceinline__ unsigned short f2bf(float f) {
  union { float f; unsigned u; } c; c.f = f;
  unsigned u = c.u + 0x7fffu + ((c.u >> 16) & 1u);  // RNE
  return (unsigned short)(u >> 16);
}

// async 16B global -> LDS (linear dest: wave-uniform base + lane*16)
__device__ __forceinline__ void gl16(const void* g, void* l) {
  __builtin_amdgcn_global_load_lds(
      (const __attribute__((address_space(1))) void*)g,
      (__attribute__((address_space(3))) void*)l, 16, 0, 0);
}

// LDS byte offset inside a 32KB operand region laid out [qtr][half][32 rows][64 cols bf16]
__device__ __forceinline__ int lds_off(int rr, int ks, int lq) {
  return (((rr >> 5) & 3) << 13) | (((rr >> 7) & 1) << 12) | ((rr & 31) << 7) | (ks << 6) | (lq << 4);
}

// ---------------- pre-pass: x->bf16 || wgub = bf16(Wgu + SCALE*Bgu@Agu) || wdb = bf16(Wd + SCALE*Bd@Ad)
__global__ __launch_bounds__(256) void k_pre(const float* __restrict__ x,
                                             unsigned short* __restrict__ xb,
                                             const float* __restrict__ Wgu,
                                             const float* __restrict__ Agu,
                                             const float* __restrict__ Bgu,
                                             unsigned short* __restrict__ wgub,
                                             const float* __restrict__ Wd,
                                             const float* __restrict__ Ad,
                                             const float* __restrict__ Bd,
                                             unsigned short* __restrict__ wdb) {
  const int NB_X = 1024, NB_GU = 8192;  // + 4096 for Wd
  int bb = blockIdx.x, tid = threadIdx.x;
  if (bb < NB_X) {
    const long n = (long)E_ * T_ * H_;
    long i = ((long)bb * 256 + tid) * 8;
    const long stride = (long)NB_X * 256 * 8;
    for (; i < n; i += stride) {
      f32x4 a = *(const f32x4*)(x + i);
      f32x4 b = *(const f32x4*)(x + i + 4);
      ushort4 lo, hi;
      lo.x=f2bf(a[0]); lo.y=f2bf(a[1]); lo.z=f2bf(a[2]); lo.w=f2bf(a[3]);
      hi.x=f2bf(b[0]); hi.y=f2bf(b[1]); hi.z=f2bf(b[2]); hi.w=f2bf(b[3]);
      *(ushort4*)(xb + i) = lo;
      *(ushort4*)(xb + i + 4) = hi;
    }
  } else if (bb < NB_X + NB_GU) {
    int b2 = bb - NB_X;
    int e = b2 >> 10;
    int o8 = (b2 & 1023) * 8;
    int c = tid * 8;
    f32x4 a0[8], a1[8];
    #pragma unroll
    for (int r = 0; r < 8; ++r) {
      const float* ap = Agu + ((long)e * R_ + r) * H_ + c;
      a0[r] = *(const f32x4*)ap;
      a1[r] = *(const f32x4*)(ap + 4);
    }
    #pragma unroll
    for (int o = 0; o < 8; ++o) {
      long row = (long)e * TWO_D_ + o8 + o;
      const float* bp = Bgu + row * R_;
      const float* wp = Wgu + row * (long)H_ + c;
      f32x4 w0 = *(const f32x4*)wp;
      f32x4 w1 = *(const f32x4*)(wp + 4);
      #pragma unroll
      for (int r = 0; r < 8; ++r) {
        float s = SCALE_ * bp[r];
        w0 += s * a0[r];
        w1 += s * a1[r];
      }
      ushort4 lo, hi;
      lo.x=f2bf(w0[0]); lo.y=f2bf(w0[1]); lo.z=f2bf(w0[2]); lo.w=f2bf(w0[3]);
      hi.x=f2bf(w1[0]); hi.y=f2bf(w1[1]); hi.z=f2bf(w1[2]); hi.w=f2bf(w1[3]);
      unsigned short* op = wgub + row * (long)H_ + c;
      *(ushort4*)op = lo;
      *(ushort4*)(op + 4) = hi;
    }
  } else {
    int b2 = bb - NB_X - NB_GU;
    int e = b2 >> 9;
    int rem = b2 & 511;
    int h8 = (rem >> 1) * 8;
    int c = (rem & 1) * 2048 + tid * 8;
    f32x4 a0[8], a1[8];
    #pragma unroll
    for (int r = 0; r < 8; ++r) {
      const float* ap = Ad + ((long)e * R_ + r) * D_ + c;
      a0[r] = *(const f32x4*)ap;
      a1[r] = *(const f32x4*)(ap + 4);
    }
    #pragma unroll
    for (int o = 0; o < 8; ++o) {
      long row = (long)e * H_ + h8 + o;
      const float* bp = Bd + row * R_;
      const float* wp = Wd + row * (long)D_ + c;
      f32x4 w0 = *(const f32x4*)wp;
      f32x4 w1 = *(const f32x4*)(wp + 4);
      #pragma unroll
      for (int r = 0; r < 8; ++r) {
        float s = SCALE_ * bp[r];
        w0 += s * a0[r];
        w1 += s * a1[r];
      }
      ushort4 lo, hi;
      lo.x=f2bf(w0[0]); lo.y=f2bf(w0[1]); lo.z=f2bf(w0[2]); lo.w=f2bf(w0[3]);
      hi.x=f2bf(w1[0]); hi.y=f2bf(w1[1]); hi.z=f2bf(w1[2]); hi.w=f2bf(w1[3]);
      unsigned short* op = wdb + row * (long)D_ + c;
      *(ushort4*)op = lo;
      *(ushort4*)(op + 4) = hi;
    }
  }
}

// ======================= GEMM1: 256x128(gate)+128(up), BK=64, 8-phase =======================
// h = up*silu(gate); gate_up = x@Wgu'^T (LoRA pre-folded into weights)
__global__ __launch_bounds__(512, 2) void k_gemm1_8p(
    const unsigned short* __restrict__ Xb, const unsigned short* __restrict__ Wb,
    unsigned short* __restrict__ Hout) {
  __shared__ __align__(16) char lds[131072];  // A: d*32768, B: 65536 + d*32768

  const int MT = T_ / 256, NT = D_ / 128;  // 8, 32
  int b = blockIdx.x;
  int cpx = (int)gridDim.x >> 3;
  int swz = (b & 7) * cpx + (b >> 3);     // bijective: grid % 8 == 0
  int e  = swz / (MT * NT);
  int r0 = swz % (MT * NT);
  int nt = r0 / MT, mt = r0 % MT;

  int tid = threadIdx.x, lane = tid & 63;
  int wid = tid >> 6, wm = wid >> 2, wn = wid & 3;
  int lrow = lane & 15, lq = lane >> 4;
  int X4 = (lrow & 7) << 4;
  const int NKT = H_ / 64;  // 32

  unsigned ro = (unsigned)tid * 16;
  unsigned so = ro ^ (((ro >> 7) & 7u) << 4);
  int sh = (so >> 12) & 1, sr = (so >> 7) & 31, sc = (so & 127) >> 1;
  const unsigned short* pA[4]; const unsigned short* pB[4];
  #pragma unroll
  for (int q = 0; q < 4; ++q) {
    long arow = (long)e * T_ + mt * 256 + sh * 128 + q * 32 + sr;
    pA[q] = Xb + arow * H_ + sc;
    long wrow = sh ? ((long)e * TWO_D_ + D_ + nt * 128 + q * 32 + sr)
                   : ((long)e * TWO_D_ +      nt * 128 + q * 32 + sr);
    pB[q] = Wb + wrow * (long)H_ + sc;
  }
  auto SA = [&](int d, int q) { gl16(pA[q], lds + d * 32768 + q * 8192 + ro); pA[q] += 64; };
  auto SB = [&](int d, int q) { gl16(pB[q], lds + 65536 + d * 32768 + q * 8192 + ro); pB[q] += 64; };

  f32x4 accg[2][8] = {}, accu[2][8] = {};  // [nj][mi]
  short8 BG[2][2], BU[2][2], af[2][2];

  SA(0,0); SB(0,0); SA(0,1); SB(0,1); SA(0,2); SB(0,2); SA(0,3); SB(0,3);
  SA(1,0); SB(1,0); SA(1,1); SB(1,1); SA(1,2); SB(1,2);
  asm volatile("s_waitcnt vmcnt(6)" ::: "memory");
  __builtin_amdgcn_s_barrier();

  int rbA = wm * 128 + lrow;
  for (int t = 0; t < NKT; ++t) {
    int d = t & 1;
    const char* Ab = lds + d * 32768;
    const char* Bb = lds + 65536 + d * 32768;

#define G1_MFMA(q)                                                                   \
    __builtin_amdgcn_s_setprio(1);                                                   \
    _Pragma("unroll") for (int m2 = 0; m2 < 2; ++m2)                                 \
      _Pragma("unroll") for (int ks = 0; ks < 2; ++ks)                               \
        _Pragma("unroll") for (int nj = 0; nj < 2; ++nj) {                           \
          accg[nj][(q)*2+m2] = __builtin_amdgcn_mfma_f32_16x16x32_bf16(              \
              BG[nj][ks], af[m2][ks], accg[nj][(q)*2+m2], 0, 0, 0);                  \
          accu[nj][(q)*2+m2] = __builtin_amdgcn_mfma_f32_16x16x32_bf16(              \
              BU[nj][ks], af[m2][ks], accu[nj][(q)*2+m2], 0, 0, 0);                  \
        }                                                                            \
    __builtin_amdgcn_s_setprio(0);

#define G1_LDA(q)                                                                    \
    _Pragma("unroll") for (int m2 = 0; m2 < 2; ++m2)                                 \
      _Pragma("unroll") for (int ks = 0; ks < 2; ++ks)                               \
        af[m2][ks] = *(const short8*)(Ab + (lds_off(rbA + ((q)*2+m2)*16, ks, lq) ^ X4));

// template-conformant sync: barrier + lgkmcnt(0); NO sched_barrier — C++ ds_reads carry
// compiler-tracked deps, so MFMAs may hoist past the drain onto operands that landed early.
#define G1_SYNC()                                                                    \
    __builtin_amdgcn_s_barrier();                                                    \
    asm volatile("s_waitcnt lgkmcnt(0)" ::: "memory");

    // phase 0: B-frags + A-quad0; stage tile t+1 last units
    #pragma unroll
    for (int nj = 0; nj < 2; ++nj)
      #pragma unroll
      for (int ks = 0; ks < 2; ++ks) {
        int rg = wn * 32 + nj * 16 + lrow;
        BG[nj][ks] = *(const short8*)(Bb + (lds_off(rg, ks, lq) ^ X4));
        BU[nj][ks] = *(const short8*)(Bb + (lds_off(rg + 128, ks, lq) ^ X4));
      }
    G1_LDA(0);
    if (t + 1 < NKT) { SA(d ^ 1, 3); SB(d ^ 1, 3); }
    G1_SYNC();
    G1_MFMA(0);
    __builtin_amdgcn_s_barrier();
    // phase 1
    G1_LDA(1);
    if (t + 2 < NKT) { SA(d, 0); SB(d, 0); }
    G1_SYNC();
    G1_MFMA(1);
    __builtin_amdgcn_s_barrier();
    // phase 2
    G1_LDA(2);
    if (t + 2 < NKT) { SA(d, 1); SB(d, 1); }
    G1_SYNC();
    G1_MFMA(2);
    __builtin_amdgcn_s_barrier();
    // phase 3 (counted vmcnt: 6 loads of tile t+2 may stay in flight)
    G1_LDA(3);
    if (t + 2 < NKT) {
      SA(d, 2); SB(d, 2);
      asm volatile("s_waitcnt vmcnt(6)" ::: "memory");
    } else {
      asm volatile("s_waitcnt vmcnt(0)" ::: "memory");
    }
    G1_SYNC();
    G1_MFMA(3);
    __builtin_amdgcn_s_barrier();
  }

  // ---- epilogue: silu + pack -> sT [256][136], then coalesced store
  __syncthreads();
  unsigned short* sT = (unsigned short*)(lds + 32768);
  #pragma unroll
  for (int mi = 0; mi < 8; ++mi) {
    int tl = rbA + mi * 16;
    #pragma unroll
    for (int nj = 0; nj < 2; ++nj) {
      int cb = wn * 32 + nj * 16 + lq * 4;
      ushort4 o;
      #pragma unroll
      for (int j = 0; j < 4; ++j) {
        float gate = accg[nj][mi][j];
        float up   = accu[nj][mi][j];
        float hh = up * (gate / (1.f + __expf(-gate)));
        (&o.x)[j] = f2bf(hh);
      }
      *(ushort4*)(sT + tl * 136 + cb) = o;
    }
  }
  __syncthreads();
  {
    long base = ((long)e * T_ + mt * 256) * D_ + nt * 128;
    int rr2 = tid >> 4, cc2 = (tid & 15) * 8;
    #pragma unroll
    for (int p = 0; p < 8; ++p) {
      int r = p * 32 + rr2;
      short8 v = *(const short8*)(sT + r * 136 + cc2);
      *(short8*)(Hout + base + (long)r * D_ + cc2) = v;
    }
  }
}

// ======================= GEMM2: 256x256, BK=64, 8-phase =======================
// out = h@Wd'^T (fp32 out; LoRA pre-folded into weights)
__global__ __launch_bounds__(512, 2) void k_gemm2_8p(
    const unsigned short* __restrict__ Hin, const unsigned short* __restrict__ Wdb,
    float* __restrict__ Out) {
  __shared__ __align__(16) char lds[131072];

  const int MT = T_ / 256, NT = H_ / 256;  // 8, 8
  int b = blockIdx.x;
  int cpx = (int)gridDim.x >> 3;
  int swz = (b & 7) * cpx + (b >> 3);
  int e  = swz / (MT * NT);
  int r0 = swz % (MT * NT);
  int nt = r0 / MT, mt = r0 % MT;

  int tid = threadIdx.x, lane = tid & 63;
  int wid = tid >> 6, wm = wid >> 2, wn = wid & 3;
  int lrow = lane & 15, lq = lane >> 4;
  int X4 = (lrow & 7) << 4;
  const int NKT = D_ / 64;  // 64

  unsigned ro = (unsigned)tid * 16;
  unsigned so = ro ^ (((ro >> 7) & 7u) << 4);
  int sh = (so >> 12) & 1, sr = (so >> 7) & 31, sc = (so & 127) >> 1;
  const unsigned short* pA[4]; const unsigned short* pB[4];
  #pragma unroll
  for (int q = 0; q < 4; ++q) {
    long arow = (long)e * T_ + mt * 256 + sh * 128 + q * 32 + sr;
    pA[q] = Hin + arow * D_ + sc;
    long wrow = (long)e * H_ + nt * 256 + sh * 128 + q * 32 + sr;
    pB[q] = Wdb + wrow * (long)D_ + sc;
  }
  auto SA = [&](int d, int q) { gl16(pA[q], lds + d * 32768 + q * 8192 + ro); pA[q] += 64; };
  auto SB = [&](int d, int q) { gl16(pB[q], lds + 65536 + d * 32768 + q * 8192 + ro); pB[q] += 64; };

  f32x4 acc[8][4] = {};  // [mi][ni]
  short8 BF[4][2], af[2][2];

  SA(0,0); SB(0,0); SA(0,1); SB(0,1); SA(0,2); SB(0,2); SA(0,3); SB(0,3);
  SA(1,0); SB(1,0); SA(1,1); SB(1,1); SA(1,2); SB(1,2);
  asm volatile("s_waitcnt vmcnt(6)" ::: "memory");
  __builtin_amdgcn_s_barrier();

  int rbA = wm * 128 + lrow;
  for (int t = 0; t < NKT; ++t) {
    int d = t & 1;
    const char* Ab = lds + d * 32768;
    const char* Bb = lds + 65536 + d * 32768;

#define G2_MFMA(q)                                                                   \
    __builtin_amdgcn_s_setprio(1);                                                   \
    _Pragma("unroll") for (int m2 = 0; m2 < 2; ++m2)                                 \
      _Pragma("unroll") for (int ks = 0; ks < 2; ++ks)                               \
        _Pragma("unroll") for (int ni = 0; ni < 4; ++ni)                             \
          acc[(q)*2+m2][ni] = __builtin_amdgcn_mfma_f32_16x16x32_bf16(               \
              af[m2][ks], BF[ni][ks], acc[(q)*2+m2][ni], 0, 0, 0);                   \
    __builtin_amdgcn_s_setprio(0);

#define G2_LDA(q)                                                                    \
    _Pragma("unroll") for (int m2 = 0; m2 < 2; ++m2)                                 \
      _Pragma("unroll") for (int ks = 0; ks < 2; ++ks)                               \
        af[m2][ks] = *(const short8*)(Ab + (lds_off(rbA + ((q)*2+m2)*16, ks, lq) ^ X4));

#define G2_SYNC()                                                                    \
    __builtin_amdgcn_s_barrier();                                                    \
    asm volatile("s_waitcnt lgkmcnt(0)" ::: "memory");

    // phase 0
    #pragma unroll
    for (int ni = 0; ni < 4; ++ni)
      #pragma unroll
      for (int ks = 0; ks < 2; ++ks)
        BF[ni][ks] = *(const short8*)(Bb + (lds_off(wn * 64 + ni * 16 + lrow, ks, lq) ^ X4));
    G2_LDA(0);
    if (t + 1 < NKT) { SA(d ^ 1, 3); SB(d ^ 1, 3); }
    G2_SYNC();
    G2_MFMA(0);
    __builtin_amdgcn_s_barrier();
    // phase 1
    G2_LDA(1);
    if (t + 2 < NKT) { SA(d, 0); SB(d, 0); }
    G2_SYNC();
    G2_MFMA(1);
    __builtin_amdgcn_s_barrier();
    // phase 2
    G2_LDA(2);
    if (t + 2 < NKT) { SA(d, 1); SB(d, 1); }
    G2_SYNC();
    G2_MFMA(2);
    __builtin_amdgcn_s_barrier();
    // phase 3
    G2_LDA(3);
    if (t + 2 < NKT) {
      SA(d, 2); SB(d, 2);
      asm volatile("s_waitcnt vmcnt(6)" ::: "memory");
    } else {
      asm volatile("s_waitcnt vmcnt(0)" ::: "memory");
    }
    G2_SYNC();
    G2_MFMA(3);
    __builtin_amdgcn_s_barrier();
  }

  // ---- epilogue: direct (row-major) stores
  {
    long rowbase = (long)e * T_ + mt * 256 + wm * 128;
    int colbase = nt * 256 + wn * 64;
    #pragma unroll
    for (int mi = 0; mi < 8; ++mi)
      #pragma unroll
      for (int j = 0; j < 4; ++j) {
        long row = rowbase + mi * 16 + lq * 4 + j;
        #pragma unroll
        for (int ni = 0; ni < 4; ++ni)
          Out[row * H_ + colbase + ni * 16 + lrow] = acc[mi][ni][j];
      }
  }
}

extern "C" void kernel_launch(void* const* d_in, const int* in_sizes, int n_in,
                              void* d_out, int out_size, void* d_ws, size_t ws_size,
                              hipStream_t stream) {
  const float* x   = (const float*)d_in[0];
  const float* Wgu = (const float*)d_in[1];
  const float* Agu = (const float*)d_in[2];
  const float* Bgu = (const float*)d_in[3];
  const float* Wd  = (const float*)d_in[4];
  const float* Ad  = (const float*)d_in[5];
  const float* Bd  = (const float*)d_in[6];
  float* out = (float*)d_out;

  char* ws = (char*)d_ws;
  const size_t SZ_H   = (size_t)E_ * T_ * D_ * 2;        // 128 MiB bf16 h
  const size_t SZ_LOW = (size_t)E_ * T_ * R_ * 4;        // layout stability
  const size_t SZ_XB  = (size_t)E_ * T_ * H_ * 2;        // 64 MiB
  const size_t SZ_WGU = (size_t)E_ * TWO_D_ * H_ * 2;    // 256 MiB

  unsigned short* hbuf = (unsigned short*)ws;
  unsigned short* xb   = (unsigned short*)(ws + SZ_H + 2 * SZ_LOW);
  unsigned short* wgub = (unsigned short*)(ws + SZ_H + 2 * SZ_LOW + SZ_XB);
  unsigned short* wdb  = (unsigned short*)(ws + SZ_H + 2 * SZ_LOW + SZ_XB + SZ_WGU);

  hipLaunchKernelGGL(k_pre, dim3(1024 + 8192 + 4096), dim3(256), 0, stream,
                     x, xb, Wgu, Agu, Bgu, wgub, Wd, Ad, Bd, wdb);
  hipLaunchKernelGGL(k_gemm1_8p, dim3(E_ * (T_ / 256) * (D_ / 128)), dim3(512), 0, stream,
                     xb, wgub, hbuf);
  hipLaunchKernelGGL(k_gemm2_8p, dim3(E_ * (T_ / 256) * (H_ / 256)), dim3(512), 0, stream,
                     hbuf, wdb, out);
}

// Round 16
// 978.981 us; speedup vs baseline: 1.0245x; 1.0245x over previous
//
#include <hip/hip_runtime.h>
#include <hip/hip_bf16.h>

#define E_ 8
#define H_ 2048
#define D_ 4096
#define R_ 8
#define T_ 2048
#define TWO_D_ 8192
#define SCALE_ 2.0f

typedef __attribute__((ext_vector_type(8))) short short8;
typedef __attribute__((ext_vector_type(4))) float f32x4;

__device__ __forceinline__ unsigned short f2bf(float f) {
  union { float f; unsigned u; } c; c.f = f;
  unsigned u = c.u + 0x7fffu + ((c.u >> 16) & 1u);  // RNE
  return (unsigned short)(u >> 16);
}

// async 16B global -> LDS (linear dest: wave-uniform base + lane*16)
__device__ __forceinline__ void gl16(const void* g, void* l) {
  __builtin_amdgcn_global_load_lds(
      (const __attribute__((address_space(1))) void*)g,
      (__attribute__((address_space(3))) void*)l, 16, 0, 0);
}

// LDS byte offset inside a 32KB operand region laid out [qtr][half][32 rows][64 cols bf16]
__device__ __forceinline__ int lds_off(int rr, int ks, int lq) {
  return (((rr >> 5) & 3) << 13) | (((rr >> 7) & 1) << 12) | ((rr & 31) << 7) | (ks << 6) | (lq << 4);
}

// ---------------- pre-pass: x->bf16 || wgub = bf16(Wgu + SCALE*Bgu@Agu)
__global__ __launch_bounds__(256) void k_pre(const float* __restrict__ x,
                                             unsigned short* __restrict__ xb,
                                             const float* __restrict__ Wgu,
                                             const float* __restrict__ Agu,
                                             const float* __restrict__ Bgu,
                                             unsigned short* __restrict__ wgub) {
  const int NB_X = 1024;
  int bb = blockIdx.x, tid = threadIdx.x;
  if (bb < NB_X) {
    const long n = (long)E_ * T_ * H_;
    long i = ((long)bb * 256 + tid) * 8;
    const long stride = (long)NB_X * 256 * 8;
    for (; i < n; i += stride) {
      f32x4 a = *(const f32x4*)(x + i);
      f32x4 b = *(const f32x4*)(x + i + 4);
      ushort4 lo, hi;
      lo.x=f2bf(a[0]); lo.y=f2bf(a[1]); lo.z=f2bf(a[2]); lo.w=f2bf(a[3]);
      hi.x=f2bf(b[0]); hi.y=f2bf(b[1]); hi.z=f2bf(b[2]); hi.w=f2bf(b[3]);
      *(ushort4*)(xb + i) = lo;
      *(ushort4*)(xb + i + 4) = hi;
    }
  } else {
    int b2 = bb - NB_X;
    int e = b2 >> 10;
    int o8 = (b2 & 1023) * 8;
    int c = tid * 8;
    f32x4 a0[8], a1[8];
    #pragma unroll
    for (int r = 0; r < 8; ++r) {
      const float* ap = Agu + ((long)e * R_ + r) * H_ + c;
      a0[r] = *(const f32x4*)ap;
      a1[r] = *(const f32x4*)(ap + 4);
    }
    #pragma unroll
    for (int o = 0; o < 8; ++o) {
      long row = (long)e * TWO_D_ + o8 + o;
      const float* bp = Bgu + row * R_;
      const float* wp = Wgu + row * (long)H_ + c;
      f32x4 w0 = *(const f32x4*)wp;
      f32x4 w1 = *(const f32x4*)(wp + 4);
      #pragma unroll
      for (int r = 0; r < 8; ++r) {
        float s = SCALE_ * bp[r];
        w0 += s * a0[r];
        w1 += s * a1[r];
      }
      ushort4 lo, hi;
      lo.x=f2bf(w0[0]); lo.y=f2bf(w0[1]); lo.z=f2bf(w0[2]); lo.w=f2bf(w0[3]);
      hi.x=f2bf(w1[0]); hi.y=f2bf(w1[1]); hi.z=f2bf(w1[2]); hi.w=f2bf(w1[3]);
      unsigned short* op = wgub + row * (long)H_ + c;
      *(ushort4*)op = lo;
      *(ushort4*)(op + 4) = hi;
    }
  }
}

// ======================= GEMM1: 256x128(gate)+128(up), BK=64, 8-phase =======================
// Blocks [0,2048): h = up*silu(gate); gate_up = x@Wgu'^T.
// Blocks [2048,3072): wdb = bf16(Wd + SCALE*Bd@Ad) — each rider block covers 16 rows x D
// (1024 x 16 x 4096 = E*H*D exactly). Rides behind the GEMM waves, hiding its HBM traffic
// under gemm1 (gemm1 uses only ~12% BW). Complete at kernel boundary.
__global__ __launch_bounds__(512, 2) void k_gemm1_8p(
    const unsigned short* __restrict__ Xb, const unsigned short* __restrict__ Wb,
    unsigned short* __restrict__ Hout,
    const float* __restrict__ Wd, const float* __restrict__ Ad,
    const float* __restrict__ Bd, unsigned short* __restrict__ wdb) {
  const int NBG = 2048;  // gemm blocks
  if ((int)blockIdx.x >= NBG) {
    // ---- Wd fold: block = 16 rows x 4096 cols; thread = 8 cols (512*8 = 4096)
    int b2 = blockIdx.x - NBG;      // [0,1024)
    int tid = threadIdx.x;          // [0,512)
    int e = b2 >> 7;                // 128 blocks/expert -> e in [0,8)
    int h16 = (b2 & 127) * 16;      // 128*16 = 2048 = H rows/expert
    int c = tid * 8;
    f32x4 a0[8], a1[8];
    #pragma unroll
    for (int r = 0; r < 8; ++r) {
      const float* ap = Ad + ((long)e * R_ + r) * D_ + c;
      a0[r] = *(const f32x4*)ap;
      a1[r] = *(const f32x4*)(ap + 4);
    }
    for (int o = 0; o < 16; ++o) {
      long row = (long)e * H_ + h16 + o;
      const float* bp = Bd + row * R_;
      const float* wp = Wd + row * (long)D_ + c;
      f32x4 w0 = *(const f32x4*)wp;
      f32x4 w1 = *(const f32x4*)(wp + 4);
      #pragma unroll
      for (int r = 0; r < 8; ++r) {
        float s = SCALE_ * bp[r];
        w0 += s * a0[r];
        w1 += s * a1[r];
      }
      ushort4 lo, hi;
      lo.x=f2bf(w0[0]); lo.y=f2bf(w0[1]); lo.z=f2bf(w0[2]); lo.w=f2bf(w0[3]);
      hi.x=f2bf(w1[0]); hi.y=f2bf(w1[1]); hi.z=f2bf(w1[2]); hi.w=f2bf(w1[3]);
      unsigned short* op = wdb + row * (long)D_ + c;
      *(ushort4*)op = lo;
      *(ushort4*)(op + 4) = hi;
    }
    return;
  }

  __shared__ __align__(16) char lds[131072];  // A: d*32768, B: 65536 + d*32768

  const int MT = T_ / 256, NT = D_ / 128;  // 8, 32
  int b = blockIdx.x;
  int cpx = NBG >> 3;
  int swz = (b & 7) * cpx + (b >> 3);     // bijective over the 2048 gemm blocks
  int e  = swz / (MT * NT);
  int r0 = swz % (MT * NT);
  int nt = r0 / MT, mt = r0 % MT;

  int tid = threadIdx.x, lane = tid & 63;
  int wid = tid >> 6, wm = wid >> 2, wn = wid & 3;
  int lrow = lane & 15, lq = lane >> 4;
  int X4 = (lrow & 7) << 4;
  const int NKT = H_ / 64;  // 32

  unsigned ro = (unsigned)tid * 16;
  unsigned so = ro ^ (((ro >> 7) & 7u) << 4);
  int sh = (so >> 12) & 1, sr = (so >> 7) & 31, sc = (so & 127) >> 1;
  const unsigned short* pA[4]; const unsigned short* pB[4];
  #pragma unroll
  for (int q = 0; q < 4; ++q) {
    long arow = (long)e * T_ + mt * 256 + sh * 128 + q * 32 + sr;
    pA[q] = Xb + arow * H_ + sc;
    long wrow = sh ? ((long)e * TWO_D_ + D_ + nt * 128 + q * 32 + sr)
                   : ((long)e * TWO_D_ +      nt * 128 + q * 32 + sr);
    pB[q] = Wb + wrow * (long)H_ + sc;
  }
  auto SA = [&](int d, int q) { gl16(pA[q], lds + d * 32768 + q * 8192 + ro); pA[q] += 64; };
  auto SB = [&](int d, int q) { gl16(pB[q], lds + 65536 + d * 32768 + q * 8192 + ro); pB[q] += 64; };

  f32x4 accg[2][8] = {}, accu[2][8] = {};  // [nj][mi]
  short8 BG[2][2], BU[2][2], af[2][2];

  SA(0,0); SB(0,0); SA(0,1); SB(0,1); SA(0,2); SB(0,2); SA(0,3); SB(0,3);
  SA(1,0); SB(1,0); SA(1,1); SB(1,1); SA(1,2); SB(1,2);
  asm volatile("s_waitcnt vmcnt(6)" ::: "memory");
  __builtin_amdgcn_s_barrier();

  int rbA = wm * 128 + lrow;
  for (int t = 0; t < NKT; ++t) {
    int d = t & 1;
    const char* Ab = lds + d * 32768;
    const char* Bb = lds + 65536 + d * 32768;

#define G1_MFMA(q)                                                                   \
    __builtin_amdgcn_s_setprio(1);                                                   \
    _Pragma("unroll") for (int m2 = 0; m2 < 2; ++m2)                                 \
      _Pragma("unroll") for (int ks = 0; ks < 2; ++ks)                               \
        _Pragma("unroll") for (int nj = 0; nj < 2; ++nj) {                           \
          accg[nj][(q)*2+m2] = __builtin_amdgcn_mfma_f32_16x16x32_bf16(              \
              BG[nj][ks], af[m2][ks], accg[nj][(q)*2+m2], 0, 0, 0);                  \
          accu[nj][(q)*2+m2] = __builtin_amdgcn_mfma_f32_16x16x32_bf16(              \
              BU[nj][ks], af[m2][ks], accu[nj][(q)*2+m2], 0, 0, 0);                  \
        }                                                                            \
    __builtin_amdgcn_s_setprio(0);

#define G1_LDA(q)                                                                    \
    _Pragma("unroll") for (int m2 = 0; m2 < 2; ++m2)                                 \
      _Pragma("unroll") for (int ks = 0; ks < 2; ++ks)                               \
        af[m2][ks] = *(const short8*)(Ab + (lds_off(rbA + ((q)*2+m2)*16, ks, lq) ^ X4));

#define G1_SYNC()                                                                    \
    __builtin_amdgcn_s_barrier();                                                    \
    asm volatile("s_waitcnt lgkmcnt(0)" ::: "memory");

    // phase 0: B-frags + A-quad0; stage tile t+1 last units
    #pragma unroll
    for (int nj = 0; nj < 2; ++nj)
      #pragma unroll
      for (int ks = 0; ks < 2; ++ks) {
        int rg = wn * 32 + nj * 16 + lrow;
        BG[nj][ks] = *(const short8*)(Bb + (lds_off(rg, ks, lq) ^ X4));
        BU[nj][ks] = *(const short8*)(Bb + (lds_off(rg + 128, ks, lq) ^ X4));
      }
    G1_LDA(0);
    if (t + 1 < NKT) { SA(d ^ 1, 3); SB(d ^ 1, 3); }
    G1_SYNC();
    G1_MFMA(0);
    __builtin_amdgcn_s_barrier();
    // phase 1
    G1_LDA(1);
    if (t + 2 < NKT) { SA(d, 0); SB(d, 0); }
    G1_SYNC();
    G1_MFMA(1);
    __builtin_amdgcn_s_barrier();
    // phase 2
    G1_LDA(2);
    if (t + 2 < NKT) { SA(d, 1); SB(d, 1); }
    G1_SYNC();
    G1_MFMA(2);
    __builtin_amdgcn_s_barrier();
    // phase 3 (counted vmcnt: 6 loads of tile t+2 may stay in flight)
    G1_LDA(3);
    if (t + 2 < NKT) {
      SA(d, 2); SB(d, 2);
      asm volatile("s_waitcnt vmcnt(6)" ::: "memory");
    } else {
      asm volatile("s_waitcnt vmcnt(0)" ::: "memory");
    }
    G1_SYNC();
    G1_MFMA(3);
    __builtin_amdgcn_s_barrier();
  }

  // ---- epilogue: silu + pack -> sT [256][136], then coalesced store
  __syncthreads();
  unsigned short* sT = (unsigned short*)(lds + 32768);
  #pragma unroll
  for (int mi = 0; mi < 8; ++mi) {
    int tl = rbA + mi * 16;
    #pragma unroll
    for (int nj = 0; nj < 2; ++nj) {
      int cb = wn * 32 + nj * 16 + lq * 4;
      ushort4 o;
      #pragma unroll
      for (int j = 0; j < 4; ++j) {
        float gate = accg[nj][mi][j];
        float up   = accu[nj][mi][j];
        float hh = up * (gate / (1.f + __expf(-gate)));
        (&o.x)[j] = f2bf(hh);
      }
      *(ushort4*)(sT + tl * 136 + cb) = o;
    }
  }
  __syncthreads();
  {
    long base = ((long)e * T_ + mt * 256) * D_ + nt * 128;
    int rr2 = tid >> 4, cc2 = (tid & 15) * 8;
    #pragma unroll
    for (int p = 0; p < 8; ++p) {
      int r = p * 32 + rr2;
      short8 v = *(const short8*)(sT + r * 136 + cc2);
      *(short8*)(Hout + base + (long)r * D_ + cc2) = v;
    }
  }
}

// ======================= GEMM2: 256x256, BK=64, 8-phase =======================
// out = h@Wd'^T (fp32 out; LoRA pre-folded into weights)
__global__ __launch_bounds__(512, 2) void k_gemm2_8p(
    const unsigned short* __restrict__ Hin, const unsigned short* __restrict__ Wdb,
    float* __restrict__ Out) {
  __shared__ __align__(16) char lds[131072];

  const int MT = T_ / 256, NT = H_ / 256;  // 8, 8
  int b = blockIdx.x;
  int cpx = (int)gridDim.x >> 3;
  int swz = (b & 7) * cpx + (b >> 3);
  int e  = swz / (MT * NT);
  int r0 = swz % (MT * NT);
  int nt = r0 / MT, mt = r0 % MT;

  int tid = threadIdx.x, lane = tid & 63;
  int wid = tid >> 6, wm = wid >> 2, wn = wid & 3;
  int lrow = lane & 15, lq = lane >> 4;
  int X4 = (lrow & 7) << 4;
  const int NKT = D_ / 64;  // 64

  unsigned ro = (unsigned)tid * 16;
  unsigned so = ro ^ (((ro >> 7) & 7u) << 4);
  int sh = (so >> 12) & 1, sr = (so >> 7) & 31, sc = (so & 127) >> 1;
  const unsigned short* pA[4]; const unsigned short* pB[4];
  #pragma unroll
  for (int q = 0; q < 4; ++q) {
    long arow = (long)e * T_ + mt * 256 + sh * 128 + q * 32 + sr;
    pA[q] = Hin + arow * D_ + sc;
    long wrow = (long)e * H_ + nt * 256 + sh * 128 + q * 32 + sr;
    pB[q] = Wdb + wrow * (long)D_ + sc;
  }
  auto SA = [&](int d, int q) { gl16(pA[q], lds + d * 32768 + q * 8192 + ro); pA[q] += 64; };
  auto SB = [&](int d, int q) { gl16(pB[q], lds + 65536 + d * 32768 + q * 8192 + ro); pB[q] += 64; };

  f32x4 acc[8][4] = {};  // [mi][ni]
  short8 BF[4][2], af[2][2];

  SA(0,0); SB(0,0); SA(0,1); SB(0,1); SA(0,2); SB(0,2); SA(0,3); SB(0,3);
  SA(1,0); SB(1,0); SA(1,1); SB(1,1); SA(1,2); SB(1,2);
  asm volatile("s_waitcnt vmcnt(6)" ::: "memory");
  __builtin_amdgcn_s_barrier();

  int rbA = wm * 128 + lrow;
  for (int t = 0; t < NKT; ++t) {
    int d = t & 1;
    const char* Ab = lds + d * 32768;
    const char* Bb = lds + 65536 + d * 32768;

#define G2_MFMA(q)                                                                   \
    __builtin_amdgcn_s_setprio(1);                                                   \
    _Pragma("unroll") for (int m2 = 0; m2 < 2; ++m2)                                 \
      _Pragma("unroll") for (int ks = 0; ks < 2; ++ks)                               \
        _Pragma("unroll") for (int ni = 0; ni < 4; ++ni)                             \
          acc[(q)*2+m2][ni] = __builtin_amdgcn_mfma_f32_16x16x32_bf16(               \
              af[m2][ks], BF[ni][ks], acc[(q)*2+m2][ni], 0, 0, 0);                   \
    __builtin_amdgcn_s_setprio(0);

#define G2_LDA(q)                                                                    \
    _Pragma("unroll") for (int m2 = 0; m2 < 2; ++m2)                                 \
      _Pragma("unroll") for (int ks = 0; ks < 2; ++ks)                               \
        af[m2][ks] = *(const short8*)(Ab + (lds_off(rbA + ((q)*2+m2)*16, ks, lq) ^ X4));

#define G2_SYNC()                                                                    \
    __builtin_amdgcn_s_barrier();                                                    \
    asm volatile("s_waitcnt lgkmcnt(0)" ::: "memory");

    // phase 0
    #pragma unroll
    for (int ni = 0; ni < 4; ++ni)
      #pragma unroll
      for (int ks = 0; ks < 2; ++ks)
        BF[ni][ks] = *(const short8*)(Bb + (lds_off(wn * 64 + ni * 16 + lrow, ks, lq) ^ X4));
    G2_LDA(0);
    if (t + 1 < NKT) { SA(d ^ 1, 3); SB(d ^ 1, 3); }
    G2_SYNC();
    G2_MFMA(0);
    __builtin_amdgcn_s_barrier();
    // phase 1
    G2_LDA(1);
    if (t + 2 < NKT) { SA(d, 0); SB(d, 0); }
    G2_SYNC();
    G2_MFMA(1);
    __builtin_amdgcn_s_barrier();
    // phase 2
    G2_LDA(2);
    if (t + 2 < NKT) { SA(d, 1); SB(d, 1); }
    G2_SYNC();
    G2_MFMA(2);
    __builtin_amdgcn_s_barrier();
    // phase 3
    G2_LDA(3);
    if (t + 2 < NKT) {
      SA(d, 2); SB(d, 2);
      asm volatile("s_waitcnt vmcnt(6)" ::: "memory");
    } else {
      asm volatile("s_waitcnt vmcnt(0)" ::: "memory");
    }
    G2_SYNC();
    G2_MFMA(3);
    __builtin_amdgcn_s_barrier();
  }

  // ---- epilogue: direct (row-major) stores
  {
    long rowbase = (long)e * T_ + mt * 256 + wm * 128;
    int colbase = nt * 256 + wn * 64;
    #pragma unroll
    for (int mi = 0; mi < 8; ++mi)
      #pragma unroll
      for (int j = 0; j < 4; ++j) {
        long row = rowbase + mi * 16 + lq * 4 + j;
        #pragma unroll
        for (int ni = 0; ni < 4; ++ni)
          Out[row * H_ + colbase + ni * 16 + lrow] = acc[mi][ni][j];
      }
  }
}

extern "C" void kernel_launch(void* const* d_in, const int* in_sizes, int n_in,
                              void* d_out, int out_size, void* d_ws, size_t ws_size,
                              hipStream_t stream) {
  const float* x   = (const float*)d_in[0];
  const float* Wgu = (const float*)d_in[1];
  const float* Agu = (const float*)d_in[2];
  const float* Bgu = (const float*)d_in[3];
  const float* Wd  = (const float*)d_in[4];
  const float* Ad  = (const float*)d_in[5];
  const float* Bd  = (const float*)d_in[6];
  float* out = (float*)d_out;

  char* ws = (char*)d_ws;
  const size_t SZ_H   = (size_t)E_ * T_ * D_ * 2;        // 128 MiB bf16 h
  const size_t SZ_LOW = (size_t)E_ * T_ * R_ * 4;        // layout stability
  const size_t SZ_XB  = (size_t)E_ * T_ * H_ * 2;        // 64 MiB
  const size_t SZ_WGU = (size_t)E_ * TWO_D_ * H_ * 2;    // 256 MiB

  unsigned short* hbuf = (unsigned short*)ws;
  unsigned short* xb   = (unsigned short*)(ws + SZ_H + 2 * SZ_LOW);
  unsigned short* wgub = (unsigned short*)(ws + SZ_H + 2 * SZ_LOW + SZ_XB);
  unsigned short* wdb  = (unsigned short*)(ws + SZ_H + 2 * SZ_LOW + SZ_XB + SZ_WGU);

  // x->bf16 (1024 blocks) || Wgu-fold->bf16 (8192 blocks)
  hipLaunchKernelGGL(k_pre, dim3(1024 + 8192), dim3(256), 0, stream,
                     x, xb, Wgu, Agu, Bgu, wgub);
  // gemm1 (2048 blocks) + Wd-fold rider (1024 blocks: 16 rows x D each, exact cover)
  hipLaunchKernelGGL(k_gemm1_8p, dim3(2048 + 1024), dim3(512), 0, stream,
                     xb, wgub, hbuf, Wd, Ad, Bd, wdb);
  hipLaunchKernelGGL(k_gemm2_8p, dim3(E_ * (T_ / 256) * (H_ / 256)), dim3(512), 0, stream,
                     hbuf, wdb, out);
}